// Round 4
// baseline (199.774 us; speedup 1.0000x reference)
//
#include <hip/hip_runtime.h>
#include <math.h>

#define B_N    131072
#define D_DIM  256
#define D4     64          // float4s per row
#define NC     16          // C*K centers
#define CPAD   65          // padded center row stride in float4 units
#define NBLK   1024        // blocks: 1024 x 4 waves x 8 groups x 4 iters = 131072 samples
#define TAU_INV    10.0f
#define MARGIN_OV  0.3f
#define MARGIN_DIV 0.8f

// ---------------- Kernel 1: fused, register-double-buffered streaming ----------------
// 1024 blocks x 256 threads (4 waves). Per wave: 32 samples, 8 lanes/sample,
// 4 pipelined iterations (prefetch i+1's z/label/rel while computing i).
// Single barrier after the center-normalize prologue; no barriers in the loop,
// so global loads stay continuously in flight (no synchronized burst-idle).
__global__ __launch_bounds__(256) void fused_kernel(
    const float* __restrict__ z,        // [B,D]
    const int*   __restrict__ labels,   // [B]
    const float* __restrict__ rel,      // [B]
    const float* __restrict__ centers,  // [16,256] raw
    const float* __restrict__ radii,    // [16] raw
    float* __restrict__ ws)             // [NBLK+2] partials
{
    __shared__ float sC[NC * CPAD * 4]; // 16 centers x 260 floats (padded)
    __shared__ float sRad[NC];          // clipped radii
    __shared__ float sRed[12];

    const int tid  = threadIdx.x;
    const int wv   = (blockIdx.x << 2) + (tid >> 6);  // 0..4095
    const int g    = (tid >> 3) & 7;                  // group in wave
    const int l    = tid & 7;                         // lane in group
    const int base = (wv << 5) + g;                   // iter i sample: base + i*8

    const float4* z4 = (const float4*)z;

    // ---- prologue: normalize 16 centers into padded LDS; clip radii ----
    {
        const int ci = tid >> 4;
        const int gl = tid & 15;
        const float4* cr4 = (const float4*)centers;
        float4* sC4w = (float4*)sC;
        float4 cv[4];
        float ssq = 0.f;
        #pragma unroll
        for (int p = 0; p < 4; ++p) {
            cv[p] = cr4[ci * D4 + p * 16 + gl];
            ssq += cv[p].x*cv[p].x + cv[p].y*cv[p].y + cv[p].z*cv[p].z + cv[p].w*cv[p].w;
        }
        #pragma unroll
        for (int m = 1; m < 16; m <<= 1) ssq += __shfl_xor(ssq, m, 64);
        const float cinv = 1.0f / fmaxf(sqrtf(ssq), 1e-12f);
        #pragma unroll
        for (int p = 0; p < 4; ++p) {
            float4 v = cv[p];
            v.x *= cinv; v.y *= cinv; v.z *= cinv; v.w *= cinv;
            sC4w[ci * CPAD + p * 16 + gl] = v;
        }
        if (tid < NC) sRad[tid] = fminf(fmaxf(fabsf(radii[tid]), 0.05f), 1.0f);
    }

    // ---- prefetch iteration 0 (hidden under prologue latency) ----
    float4 zb[2][8];
    int   lblN;
    float relN;
    {
        const int s = base;
        #pragma unroll
        for (int p = 0; p < 8; ++p) zb[0][p] = z4[s * D4 + p * 8 + l];
        lblN = labels[s];
        relN = rel[s];
    }

    __syncthreads();

    const float4* sC4 = (const float4*)sC;
    float acc = 0.f;

    #pragma unroll
    for (int i = 0; i < 4; ++i) {
        const int cur = i & 1, nxt = cur ^ 1;
        const int   lbl  = lblN;
        const float relC = relN;

        // issue next iteration's loads before consuming current (stay in flight)
        if (i < 3) {
            const int s = base + ((i + 1) << 3);
            #pragma unroll
            for (int p = 0; p < 8; ++p) zb[nxt][p] = z4[s * D4 + p * 8 + l];
            lblN = labels[s];
            relN = rel[s];
        }

        const float r0 = sRad[lbl * 2 + 0];
        const float r1 = sRad[lbl * 2 + 1];

        float zz = 0.f, d0 = 0.f, d1 = 0.f;
        #pragma unroll
        for (int p = 0; p < 8; ++p) {
            const float4 zv = zb[cur][p];
            const float4 a  = sC4[(lbl * 2 + 0) * CPAD + p * 8 + l];
            const float4 b  = sC4[(lbl * 2 + 1) * CPAD + p * 8 + l];
            zz += zv.x*zv.x + zv.y*zv.y + zv.z*zv.z + zv.w*zv.w;
            d0 += zv.x*a.x  + zv.y*a.y  + zv.z*a.z  + zv.w*a.w;
            d1 += zv.x*b.x  + zv.y*b.y  + zv.z*b.z  + zv.w*b.w;
        }
        #pragma unroll
        for (int m = 1; m < 8; m <<= 1) {
            zz += __shfl_xor(zz, m, 64);
            d0 += __shfl_xor(d0, m, 64);
            d1 += __shfl_xor(d1, m, 64);
        }
        const float invn = 1.0f / fmaxf(sqrtf(zz), 1e-12f);
        const float s0 = d0 * invn;
        const float s1 = d1 * invn;
        const float q0 = 1.0f / (1.0f + __expf((s1 - s0) * TAU_INV));
        const float val = q0 * ((1.0f - s0) - r0) + (1.0f - q0) * ((1.0f - s1) - r1);
        acc += (l == 0) ? relC * fmaxf(val, 0.f) : 0.f;
    }

    // ---- block 0 only: overlap + diversity raw sums from LDS centers ----
    float ovs = 0.f, dvs = 0.f;
    if (blockIdx.x == 0) {
        const int i = tid >> 4, j = tid & 15;   // all 256 ordered pairs
        float dot = 0.f;
        #pragma unroll 4
        for (int d = 0; d < D4; ++d) {
            const float4 a = sC4[i * CPAD + d];
            const float4 b = sC4[j * CPAD + d];
            dot += a.x*b.x + a.y*b.y + a.z*b.z + a.w*b.w;
        }
        if ((i >> 1) != (j >> 1))      ovs = fmaxf(dot - MARGIN_OV, 0.f);
        else if (i < j)                dvs = fmaxf(dot - MARGIN_DIV, 0.f);
    }

    // ---- block reduction (acc nonzero only on l==0 lanes) ----
    #pragma unroll
    for (int m = 1; m < 64; m <<= 1) {
        acc += __shfl_xor(acc, m, 64);
        ovs += __shfl_xor(ovs, m, 64);
        dvs += __shfl_xor(dvs, m, 64);
    }
    const int w = tid >> 6;
    if ((tid & 63) == 0) { sRed[w] = acc; sRed[4 + w] = ovs; sRed[8 + w] = dvs; }
    __syncthreads();
    if (tid == 0) {
        ws[blockIdx.x] = sRed[0] + sRed[1] + sRed[2] + sRed[3];
        if (blockIdx.x == 0) {
            ws[NBLK + 0] = sRed[4] + sRed[5] + sRed[6] + sRed[7];
            ws[NBLK + 1] = sRed[8] + sRed[9] + sRed[10] + sRed[11];
        }
    }
}

// ---------------- Kernel 2: final reduce (tiny) ----------------
__global__ __launch_bounds__(256) void finalize_kernel(
    const float* __restrict__ ws, float* __restrict__ out)
{
    __shared__ float sRed[4];
    const int tid = threadIdx.x;
    float a = 0.f;
    #pragma unroll
    for (int k = 0; k < NBLK / 256; ++k) a += ws[tid + k * 256];
    #pragma unroll
    for (int m = 1; m < 64; m <<= 1) a += __shfl_xor(a, m, 64);
    if ((tid & 63) == 0) sRed[tid >> 6] = a;
    __syncthreads();
    if (tid == 0) {
        const float intra = (sRed[0] + sRed[1] + sRed[2] + sRed[3]) * (1.0f / (float)B_N);
        const float l_ov  = ws[NBLK + 0] / (224.0f + 1e-6f);   // mask_sum = 16*16 - 16*2
        const float l_dv  = ws[NBLK + 1] * (1.0f / 8.0f);      // C*K*(K-1)/2
        out[0] = intra + 0.5f * l_ov + 0.5f * l_dv;
    }
}

extern "C" void kernel_launch(void* const* d_in, const int* in_sizes, int n_in,
                              void* d_out, int out_size, void* d_ws, size_t ws_size,
                              hipStream_t stream) {
    const float* z       = (const float*)d_in[0];
    const int*   labels  = (const int*)d_in[1];
    const float* rel     = (const float*)d_in[2];
    const float* centers = (const float*)d_in[3];
    const float* radii   = (const float*)d_in[4];
    float* out = (float*)d_out;
    float* wsf = (float*)d_ws;   // NBLK+2 floats used

    fused_kernel<<<NBLK, 256, 0, stream>>>(z, labels, rel, centers, radii, wsf);
    finalize_kernel<<<1, 256, 0, stream>>>(wsf, out);
}

// Round 5
// 197.545 us; speedup vs baseline: 1.0113x; 1.0113x over previous
//
#include <hip/hip_runtime.h>
#include <math.h>

#define B_N    131072
#define D_DIM  256
#define D4     64          // float4s per row
#define NC     16          // C*K centers
#define CPAD   65          // padded center row stride in float4 units
#define NBLK   1024        // blocks: 1024 x 4 waves x 8 groups x 4 iters = 131072 samples
#define TAU_INV    10.0f
#define MARGIN_OV  0.3f
#define MARGIN_DIV 0.8f

// ---------------- Single fused kernel ----------------
// 1024 blocks x 256 threads (4 waves). Per wave: 32 samples, 8 lanes/sample,
// 4 pipelined iterations (prefetch i+1's z/label/rel while computing i).
// Block partial folded into out[0] via one device-scope atomicAdd per block
// (out zeroed by a memset node in the same graph). Block 0 additionally
// computes the overlap/diversity terms.
__global__ __launch_bounds__(256) void fused_kernel(
    const float* __restrict__ z,        // [B,D]
    const int*   __restrict__ labels,   // [B]
    const float* __restrict__ rel,      // [B]
    const float* __restrict__ centers,  // [16,256] raw
    const float* __restrict__ radii,    // [16] raw
    float* __restrict__ out)            // [1], pre-zeroed by memset node
{
    __shared__ float sC[NC * CPAD * 4]; // 16 centers x 260 floats (padded)
    __shared__ float sRad[NC];          // clipped radii
    __shared__ float sRed[12];

    const int tid  = threadIdx.x;
    const int wv   = (blockIdx.x << 2) + (tid >> 6);  // 0..4095
    const int g    = (tid >> 3) & 7;                  // group in wave
    const int l    = tid & 7;                         // lane in group
    const int base = (wv << 5) + g;                   // iter i sample: base + i*8

    const float4* z4 = (const float4*)z;

    // ---- prologue: normalize 16 centers into padded LDS; clip radii ----
    {
        const int ci = tid >> 4;
        const int gl = tid & 15;
        const float4* cr4 = (const float4*)centers;
        float4* sC4w = (float4*)sC;
        float4 cv[4];
        float ssq = 0.f;
        #pragma unroll
        for (int p = 0; p < 4; ++p) {
            cv[p] = cr4[ci * D4 + p * 16 + gl];
            ssq += cv[p].x*cv[p].x + cv[p].y*cv[p].y + cv[p].z*cv[p].z + cv[p].w*cv[p].w;
        }
        #pragma unroll
        for (int m = 1; m < 16; m <<= 1) ssq += __shfl_xor(ssq, m, 64);
        const float cinv = 1.0f / fmaxf(sqrtf(ssq), 1e-12f);
        #pragma unroll
        for (int p = 0; p < 4; ++p) {
            float4 v = cv[p];
            v.x *= cinv; v.y *= cinv; v.z *= cinv; v.w *= cinv;
            sC4w[ci * CPAD + p * 16 + gl] = v;
        }
        if (tid < NC) sRad[tid] = fminf(fmaxf(fabsf(radii[tid]), 0.05f), 1.0f);
    }

    // ---- prefetch iteration 0 (hidden under prologue latency) ----
    float4 zb[2][8];
    int   lblN;
    float relN;
    {
        const int s = base;
        #pragma unroll
        for (int p = 0; p < 8; ++p) zb[0][p] = z4[s * D4 + p * 8 + l];
        lblN = labels[s];
        relN = rel[s];
    }

    __syncthreads();

    const float4* sC4 = (const float4*)sC;
    float acc = 0.f;

    #pragma unroll
    for (int i = 0; i < 4; ++i) {
        const int cur = i & 1, nxt = cur ^ 1;
        const int   lbl  = lblN;
        const float relC = relN;

        // issue next iteration's loads before consuming current (stay in flight)
        if (i < 3) {
            const int s = base + ((i + 1) << 3);
            #pragma unroll
            for (int p = 0; p < 8; ++p) zb[nxt][p] = z4[s * D4 + p * 8 + l];
            lblN = labels[s];
            relN = rel[s];
        }

        const float r0 = sRad[lbl * 2 + 0];
        const float r1 = sRad[lbl * 2 + 1];

        float zz = 0.f, d0 = 0.f, d1 = 0.f;
        #pragma unroll
        for (int p = 0; p < 8; ++p) {
            const float4 zv = zb[cur][p];
            const float4 a  = sC4[(lbl * 2 + 0) * CPAD + p * 8 + l];
            const float4 b  = sC4[(lbl * 2 + 1) * CPAD + p * 8 + l];
            zz += zv.x*zv.x + zv.y*zv.y + zv.z*zv.z + zv.w*zv.w;
            d0 += zv.x*a.x  + zv.y*a.y  + zv.z*a.z  + zv.w*a.w;
            d1 += zv.x*b.x  + zv.y*b.y  + zv.z*b.z  + zv.w*b.w;
        }
        #pragma unroll
        for (int m = 1; m < 8; m <<= 1) {
            zz += __shfl_xor(zz, m, 64);
            d0 += __shfl_xor(d0, m, 64);
            d1 += __shfl_xor(d1, m, 64);
        }
        const float invn = 1.0f / fmaxf(sqrtf(zz), 1e-12f);
        const float s0 = d0 * invn;
        const float s1 = d1 * invn;
        const float q0 = 1.0f / (1.0f + __expf((s1 - s0) * TAU_INV));
        const float val = q0 * ((1.0f - s0) - r0) + (1.0f - q0) * ((1.0f - s1) - r1);
        acc += (l == 0) ? relC * fmaxf(val, 0.f) : 0.f;
    }

    // ---- intra block reduction ----
    #pragma unroll
    for (int m = 1; m < 64; m <<= 1) acc += __shfl_xor(acc, m, 64);
    const int w = tid >> 6;
    if ((tid & 63) == 0) sRed[w] = acc;

    // ---- block 0 only: overlap + diversity from LDS centers ----
    if (blockIdx.x == 0) {
        const int i = tid >> 4, j = tid & 15;   // all 256 ordered pairs
        float dot = 0.f;
        #pragma unroll 4
        for (int d = 0; d < D4; ++d) {
            const float4 a = sC4[i * CPAD + d];
            const float4 b = sC4[j * CPAD + d];
            dot += a.x*b.x + a.y*b.y + a.z*b.z + a.w*b.w;
        }
        float ovs = 0.f, dvs = 0.f;
        if ((i >> 1) != (j >> 1))      ovs = fmaxf(dot - MARGIN_OV, 0.f);
        else if (i < j)                dvs = fmaxf(dot - MARGIN_DIV, 0.f);
        #pragma unroll
        for (int m = 1; m < 64; m <<= 1) {
            ovs += __shfl_xor(ovs, m, 64);
            dvs += __shfl_xor(dvs, m, 64);
        }
        if ((tid & 63) == 0) { sRed[4 + w] = ovs; sRed[8 + w] = dvs; }
    }

    __syncthreads();
    if (tid == 0) {
        float v = (sRed[0] + sRed[1] + sRed[2] + sRed[3]) * (1.0f / (float)B_N);
        if (blockIdx.x == 0) {
            const float ovs = sRed[4] + sRed[5] + sRed[6] + sRed[7];
            const float dvs = sRed[8] + sRed[9] + sRed[10] + sRed[11];
            v += 0.5f * (ovs / (224.0f + 1e-6f)) + 0.5f * (dvs * (1.0f / 8.0f));
        }
        atomicAdd(out, v);   // device-scope by default; 1024 total, spread over retirement
    }
}

extern "C" void kernel_launch(void* const* d_in, const int* in_sizes, int n_in,
                              void* d_out, int out_size, void* d_ws, size_t ws_size,
                              hipStream_t stream) {
    const float* z       = (const float*)d_in[0];
    const int*   labels  = (const int*)d_in[1];
    const float* rel     = (const float*)d_in[2];
    const float* centers = (const float*)d_in[3];
    const float* radii   = (const float*)d_in[4];
    float* out = (float*)d_out;

    hipMemsetAsync(out, 0, (size_t)out_size * sizeof(float), stream);
    fused_kernel<<<NBLK, 256, 0, stream>>>(z, labels, rel, centers, radii, out);
}